// Round 12
// baseline (392.955 us; speedup 1.0000x reference)
//
#include <hip/hip_runtime.h>
#include <hip/hip_bf16.h>
#include <hip/hip_fp16.h>

typedef _Float16 half8 __attribute__((ext_vector_type(8)));
typedef _Float16 half4 __attribute__((ext_vector_type(4)));
typedef __fp16 fp16x2 __attribute__((ext_vector_type(2)));
typedef float floatx4 __attribute__((ext_vector_type(4)));

#define HID 128
#define TILE_M 32

__device__ __forceinline__ float fast_silu(float v) {
    float e = __expf(-v);
    return v * __builtin_amdgcn_rcpf(1.f + e);
}

__device__ __forceinline__ unsigned int pk2(float a, float b) {
    fp16x2 h = __builtin_amdgcn_cvt_pkrtz(a, b);
    return __builtin_bit_cast(unsigned int, h);
}

// ---------------------------------------------------------------------------
// Kernel 0: pack W2 (fp32 [128][128]) into fp16 fragment layout
// P[((kc*128+c)*4+q)*8+j] = W2[(kc*32+q*8+j)*HID+c] so a wave's (kc)
// fragment load is one coalesced 1 KB block. 32 KB total: L2-resident
// (and mostly L1-resident) during the edge kernel.
// ---------------------------------------------------------------------------
__global__ __launch_bounds__(256) void prep_w2_kernel(
    const float* __restrict__ W2, _Float16* __restrict__ P)
{
    int idx = blockIdx.x * 256 + threadIdx.x;   // (kc,c,q): 4*128*4 = 2048
    if (idx >= 2048) return;
    int q = idx & 3, c = (idx >> 2) & 127, kc = idx >> 9;
    #pragma unroll
    for (int j = 0; j < 8; ++j)
        P[(size_t)idx * 8 + j] = (_Float16)W2[(kc * 32 + q * 8 + j) * HID + c];
}

// ---------------------------------------------------------------------------
// Kernel 1: node_emb = [x|pos|0-pad] @ [Wa;Wp;0] + (ba+bp). Block handles a
// 64-node tile via MFMA; output assembled in padded LDS, stored coalesced.
// ---------------------------------------------------------------------------
#define LDO 136
__global__ __launch_bounds__(256) void node_emb_kernel(
    const float* __restrict__ x, const float* __restrict__ pos,
    const float* __restrict__ Wa, const float* __restrict__ ba,
    const float* __restrict__ Wp, const float* __restrict__ bp,
    _Float16* __restrict__ nodeEmb, int N)
{
    __shared__ __align__(16) _Float16 sOut[64 * LDO];   // 17 KB
    const int t    = threadIdx.x;
    const int wave = t >> 6;
    const int lane = t & 63;
    const int quad = lane >> 4;
    const int l16  = lane & 15;

    half8 wf[2];
    floatx4 bias[2];
    #pragma unroll
    for (int ct = 0; ct < 2; ++ct) {
        int col = wave * 32 + ct * 16 + l16;
        #pragma unroll
        for (int j = 0; j < 8; ++j) {
            int k = quad * 8 + j;
            float w = 0.f;
            if (k < 16) w = Wa[k * HID + col];
            else if (k < 19) w = Wp[(k - 16) * HID + col];
            wf[ct][j] = (_Float16)w;
        }
        #pragma unroll
        for (int i = 0; i < 4; ++i) {
            int c2 = wave * 32 + ct * 16 + quad * 4 + i;
            bias[ct][i] = ba[c2] + bp[c2];
        }
    }

    int nTiles = (N + 63) >> 6;
    for (int tile = blockIdx.x; tile < nTiles; tile += gridDim.x) {
        int base = tile * 64;
        half8 af[4];
        #pragma unroll
        for (int rt = 0; rt < 4; ++rt) {
            int node = base + rt * 16 + l16;
            int nd = node < N ? node : N - 1;
            half8 a = (half8){0, 0, 0, 0, 0, 0, 0, 0};
            if (quad < 2) {
                const float* xp = x + (size_t)nd * 16 + quad * 8;
                float4 v0 = *(const float4*)xp;
                float4 v1 = *(const float4*)(xp + 4);
                a[0] = (_Float16)v0.x; a[1] = (_Float16)v0.y;
                a[2] = (_Float16)v0.z; a[3] = (_Float16)v0.w;
                a[4] = (_Float16)v1.x; a[5] = (_Float16)v1.y;
                a[6] = (_Float16)v1.z; a[7] = (_Float16)v1.w;
            } else if (quad == 2) {
                const float* pp = pos + (size_t)nd * 3;
                a[0] = (_Float16)pp[0]; a[1] = (_Float16)pp[1]; a[2] = (_Float16)pp[2];
            }
            af[rt] = a;
        }
        #pragma unroll
        for (int ct = 0; ct < 2; ++ct)
            #pragma unroll
            for (int rt = 0; rt < 4; ++rt) {
                floatx4 d = bias[ct];
                d = __builtin_amdgcn_mfma_f32_16x16x32_f16(wf[ct], af[rt], d, 0, 0, 0);
                half4 hv;
                hv[0] = (_Float16)d[0]; hv[1] = (_Float16)d[1];
                hv[2] = (_Float16)d[2]; hv[3] = (_Float16)d[3];
                *(half4*)&sOut[(rt * 16 + l16) * LDO + wave * 32 + ct * 16 + quad * 4] = hv;
            }
        __syncthreads();
        #pragma unroll
        for (int p = 0; p < 4; ++p) {
            int idx = p * 256 + t;
            int r = idx >> 4, c = idx & 15;
            int node = base + r;
            if (node < N)
                *(half8*)(nodeEmb + (size_t)node * HID + c * 8) =
                    *(const half8*)&sOut[r * LDO + c * 8];
        }
        __syncthreads();
    }
}

// ---------------------------------------------------------------------------
// Kernel 2: per-edge MLP. TILE_M=32, 512 threads = 8 waves x 16 output cols.
// r11 structure (register-staged gather, proven race-free) + REGISTER DIET.
// Occupancy model from r6/r8/r11: reported VGPR_Count excludes the MFMA
// accumulator allocation in the unified file; true/wave = VGPR + ~32(acc).
// r11: 64+32=96 -> floor(512/96)=5 wave-slots/SIMD -> only 2 resident
// 8-wave blocks (2 slots/SIMD each) -> measured 42.9%. r8: 32+32=64 ->
// 8 slots -> 4 blocks -> 91.5%. Target: reported VGPR <= ~48 so total
// <= ~85 -> 6 slots -> 3 blocks/CU. Diet:
//  - w2f (16 persistent VGPR) -> streamed per-kc from packed L2-resident
//    table w2p (4 coalesced 1KB loads/tile, layer-2 only; r4-proven pattern
//    at 1/4 the load count and off the layer-1 critical path)
//  - w1c/b1f/b2f (12 VGPR)    -> sWc/sB1/sB2 LDS tables (r3-proven)
//  - gather: issue+write immediately post-B2 (va dead before layer-2;
//    same dataflow-ordered model as r11 -> race-free)
// Peak audit: layer-1 = w1f 32 + a 8 + addr ~8 = 48; layer-2 = w1f 32 +
// wc 4 + a 8 = ~48. LDS 35.5 KB -> 2/80KB-partition -> 4 blocks LDS-wise;
// regs predicted 3. Grid 768 = 3/CU exact. launch_bounds (512,4): natural
// allocation, no forced spill (the r1/r3/r8 trap).
// Verify: VGPR <= 52 (>=60 = diet failed), WRITE ~43MB, Occupancy 60-68%.
// ---------------------------------------------------------------------------
__global__ __launch_bounds__(512, 4) void edge_mlp_kernel(
    const _Float16* __restrict__ nodeEmb,
    const _Float16* __restrict__ w2p,      // packed W2 frags [4][128][4][8]
    const float* __restrict__ pos,
    const int* __restrict__ eidx,          // [2][E]
    const float* __restrict__ W1, const float* __restrict__ b1,   // [257][128]
    const float* __restrict__ W2, const float* __restrict__ b2,   // [128][128]
    const float* __restrict__ W3, const float* __restrict__ b3,   // [128][4]
    float* __restrict__ out, int E, int nTiles)
{
    __shared__ __align__(16) _Float16 sA[2 * TILE_M * HID];   // 16 KB, XOR swizzle
    __shared__ __align__(16) _Float16 sH1[TILE_M * HID];      // 8 KB, XOR swizzle
    __shared__ __align__(16) _Float16 sH2[TILE_M * HID];      // 8 KB, XOR swizzle
    __shared__ float sDist[TILE_M];
    __shared__ __align__(16) _Float16 sW3[512];               // 1 KB  W3 frags
    __shared__ __align__(16) float sB1[HID];                  // b1
    __shared__ __align__(16) float sB2[HID];                  // b2
    __shared__ __align__(16) float sWc[HID];                  // W1 dist row

    const int t    = threadIdx.x;
    const int wave = t >> 6;               // 0..7
    const int lane = t & 63;
    const int quad = lane >> 4;
    const int l16  = lane & 15;
    const int colbase = wave * 16;         // each wave owns 16 output columns

    // ---- stage small constant tables into LDS (visible after first B1) ----
    if (t < 64) {
        int kc = t >> 4, q = (t >> 2) & 3, c = t & 3;
        #pragma unroll
        for (int j = 0; j < 8; ++j)
            sW3[(kc * 16 + q * 4 + c) * 8 + j] =
                (_Float16)W3[(kc * 32 + q * 8 + j) * 4 + c];
    }
    if (t < HID) {
        sB1[t] = b1[t];
        sB2[t] = b2[t];
        sWc[t] = W1[256 * HID + t];
    }

    // ---- persistent weight fragments: W1 only (32 VGPR) ----
    half8 w1f[8];
    {
        int col = colbase + l16;
        #pragma unroll
        for (int kc = 0; kc < 8; ++kc)
            #pragma unroll
            for (int j = 0; j < 8; ++j)
                w1f[kc][j] = (_Float16)W1[(kc * 32 + quad * 8 + j) * HID + col];
    }
    const float b3v0 = b3[0], b3v1 = b3[1], b3v2 = b3[2], b3v3 = b3[3];

    int nid[2];
    float dpre = 0.f;

    auto load_nid = [&](int tl) {
        int eb = tl * TILE_M;
        #pragma unroll
        for (int i = 0; i < 2; ++i) {
            int cid = i * 512 + t;           // 0..1023 chunks of 16B
            int row = cid >> 4;              // 0..63: 0-31 src, 32-63 dst
            int r   = row & 31;
            int e   = eb + r; if (e >= E) e = E - 1;
            nid[i] = (row >> 5) ? eidx[(size_t)E + e] : eidx[e];
        }
    };
    auto load_dist = [&](int tl) -> float {
        if (t >= TILE_M) return 0.f;
        int e = tl * TILE_M + t; if (e >= E) e = E - 1;
        int s = eidx[e], d = eidx[(size_t)E + e];
        float dx = pos[3 * (size_t)s]     - pos[3 * (size_t)d];
        float dy = pos[3 * (size_t)s + 1] - pos[3 * (size_t)d + 1];
        float dz = pos[3 * (size_t)s + 2] - pos[3 * (size_t)d + 2];
        return sqrtf(dx * dx + dy * dy + dz * dz);
    };
    // register-staged gather: global -> va regs -> ds_write (dataflow-ordered;
    // ds_writes drain at next __syncthreads via lgkmcnt). Race-free (r11).
    auto gather = [&]() {
        half8 va[2];
        #pragma unroll
        for (int i = 0; i < 2; ++i) {
            int cid = i * 512 + t;
            int row = cid >> 4;
            int cg  = (cid & 15) ^ (row & 15);      // XOR swizzle
            va[i] = *(const half8*)(nodeEmb + (size_t)nid[i] * HID + cg * 8);
        }
        #pragma unroll
        for (int i = 0; i < 2; ++i) {
            int cid = i * 512 + t;
            *(half8*)&sA[cid * 8] = va[i];
        }
    };

    bool havePrev = false;
    int prevEbase = 0;
    int tile = blockIdx.x;
    if (tile < nTiles) {
        load_nid(tile);
        dpre = load_dist(tile);
        gather();                            // published by first B1 (lgkm)
    }

    for (; tile < nTiles; tile += gridDim.x) {
        const int ebase = tile * TILE_M;
        if (t < TILE_M) sDist[t] = dpre;
        __syncthreads();                     // B1: sA(T) + sH2(T-1) visible

        // ---- layer 3 of previous tile: waves 0-1 cover the 32 edges ----
        if (havePrev && wave < 2) {
            floatx4 acc3 = (floatx4){0.f, 0.f, 0.f, 0.f};
            #pragma unroll
            for (int kc = 0; kc < 4; ++kc) {
                int slot = ((kc * 4 + quad) ^ l16) * 8;
                half8 h  = *(const half8*)&sH2[(wave * 16 + l16) * HID + slot];
                half8 w3 = *(const half8*)&sW3[(kc * 16 + quad * 4 + (l16 & 3)) * 8];
                acc3 = __builtin_amdgcn_mfma_f32_16x16x32_f16(w3, h, acc3, 0, 0, 0);
            }
            if (quad == 0) {
                int e = prevEbase + wave * 16 + l16;
                if (e < E) {
                    float4 o = {acc3[0] + b3v0, acc3[1] + b3v1,
                                acc3[2] + b3v2, acc3[3] + b3v3};
                    *(float4*)&out[(size_t)e * 4] = o;
                }
            }
        }

        // ---- prefetch next tile metadata (gather issued post-B2) ----
        int nxt = tile + gridDim.x;
        if (nxt < nTiles) {
            load_nid(nxt);
            dpre = load_dist(nxt);
        }

        // ---- layer 1: bias (LDS) in acc init, XOR-swizzled sA reads ----
        floatx4 acc[2];
        {
            floatx4 b1v = *(const floatx4*)&sB1[colbase + quad * 4];
            acc[0] = b1v; acc[1] = b1v;
        }
        #pragma unroll
        for (int kc = 0; kc < 8; ++kc) {
            int hf   = kc >> 2;
            int cg   = (kc & 3) * 4 + quad;
            int slot = (cg ^ l16) * 8;
            const _Float16* base = &sA[(hf * TILE_M + l16) * HID + slot];
            half8 a0 = *(const half8*)(base + 0 * 16 * HID);
            half8 a1 = *(const half8*)(base + 1 * 16 * HID);
            acc[0] = __builtin_amdgcn_mfma_f32_16x16x32_f16(w1f[kc], a0, acc[0], 0, 0, 0);
            acc[1] = __builtin_amdgcn_mfma_f32_16x16x32_f16(w1f[kc], a1, acc[1], 0, 0, 0);
        }
        // epilogue 1 -> sH1 (XOR-swizzled uint2 writes); w1c from LDS
        {
            floatx4 w1cv = *(const floatx4*)&sWc[colbase + quad * 4];
            #pragma unroll
            for (int rt = 0; rt < 2; ++rt) {
                int m = rt * 16 + l16;
                float d = sDist[m];
                float v0 = fast_silu(fmaf(d, w1cv[0], acc[rt][0]));
                float v1 = fast_silu(fmaf(d, w1cv[1], acc[rt][1]));
                float v2 = fast_silu(fmaf(d, w1cv[2], acc[rt][2]));
                float v3 = fast_silu(fmaf(d, w1cv[3], acc[rt][3]));
                uint2 w;
                w.x = pk2(v0, v1);
                w.y = pk2(v2, v3);
                int cgb  = wave * 2 + (quad >> 1);
                int slot = cgb ^ l16;
                *(uint2*)&sH1[m * HID + slot * 8 + (quad & 1) * 4] = w;
            }
        }
        __syncthreads();                     // B2: h1 visible, sA(T) reads done

        // ---- gather next tile into sA (sA dead since B2; va regs die here,
        //      before layer-2 — keeps layer-2 working set minimal) ----
        if (nxt < nTiles) gather();

        // ---- layer 2: bias (LDS) in acc init; W2 frags streamed per-kc
        //      from L2-resident packed table (1 KB coalesced per load) ----
        floatx4 acc2[2];
        {
            floatx4 b2v = *(const floatx4*)&sB2[colbase + quad * 4];
            acc2[0] = b2v; acc2[1] = b2v;
        }
        #pragma unroll
        for (int kc = 0; kc < 4; ++kc) {
            half8 wc = *(const half8*)(w2p +
                ((size_t)(kc * 128 + colbase + l16) * 4 + quad) * 8);
            int slot = ((kc * 4 + quad) ^ l16) * 8;
            half8 a0 = *(const half8*)&sH1[(0 * 16 + l16) * HID + slot];
            half8 a1 = *(const half8*)&sH1[(1 * 16 + l16) * HID + slot];
            acc2[0] = __builtin_amdgcn_mfma_f32_16x16x32_f16(wc, a0, acc2[0], 0, 0, 0);
            acc2[1] = __builtin_amdgcn_mfma_f32_16x16x32_f16(wc, a1, acc2[1], 0, 0, 0);
        }
        // epilogue 2 -> sH2 (all waves' L3(T-1) reads finished before B2)
        #pragma unroll
        for (int rt = 0; rt < 2; ++rt) {
            int m = rt * 16 + l16;
            float v0 = fast_silu(acc2[rt][0]);
            float v1 = fast_silu(acc2[rt][1]);
            float v2 = fast_silu(acc2[rt][2]);
            float v3 = fast_silu(acc2[rt][3]);
            uint2 w;
            w.x = pk2(v0, v1);
            w.y = pk2(v2, v3);
            int cgb  = wave * 2 + (quad >> 1);
            int slot = cgb ^ l16;
            *(uint2*)&sH2[m * HID + slot * 8 + (quad & 1) * 4] = w;
        }
        havePrev = true;
        prevEbase = ebase;
    }

    // ---- flush: layer 3 of the final tile ----
    if (havePrev) {
        __syncthreads();
        if (wave < 2) {
            floatx4 acc3 = (floatx4){0.f, 0.f, 0.f, 0.f};
            #pragma unroll
            for (int kc = 0; kc < 4; ++kc) {
                int slot = ((kc * 4 + quad) ^ l16) * 8;
                half8 h  = *(const half8*)&sH2[(wave * 16 + l16) * HID + slot];
                half8 w3 = *(const half8*)&sW3[(kc * 16 + quad * 4 + (l16 & 3)) * 8];
                acc3 = __builtin_amdgcn_mfma_f32_16x16x32_f16(w3, h, acc3, 0, 0, 0);
            }
            if (quad == 0) {
                int e = prevEbase + wave * 16 + l16;
                if (e < E) {
                    float4 o = {acc3[0] + b3v0, acc3[1] + b3v1,
                                acc3[2] + b3v2, acc3[3] + b3v3};
                    *(float4*)&out[(size_t)e * 4] = o;
                }
            }
        }
    }
}

extern "C" void kernel_launch(void* const* d_in, const int* in_sizes, int n_in,
                              void* d_out, int out_size, void* d_ws, size_t ws_size,
                              hipStream_t stream) {
    const float* x   = (const float*)d_in[0];
    const float* pos = (const float*)d_in[1];
    const int*  eidx = (const int*)d_in[2];
    const float* Wa = (const float*)d_in[3];
    const float* ba = (const float*)d_in[4];
    const float* Wp = (const float*)d_in[5];
    const float* bp = (const float*)d_in[6];
    const float* W1 = (const float*)d_in[7];
    const float* b1 = (const float*)d_in[8];
    const float* W2 = (const float*)d_in[9];
    const float* b2 = (const float*)d_in[10];
    const float* W3 = (const float*)d_in[11];
    const float* b3 = (const float*)d_in[12];
    float* out = (float*)d_out;

    int N = in_sizes[0] / 16;   // ATOM_DIM
    int E = in_sizes[2] / 2;

    _Float16* nodeEmb = (_Float16*)d_ws;                 // N*128 fp16 = 25.6 MB
    _Float16* w2p = (_Float16*)((char*)d_ws + (size_t)N * HID * 2);  // +32 KB

    prep_w2_kernel<<<8, 256, 0, stream>>>(W2, w2p);

    int nodeTiles = (N + 63) / 64;
    node_emb_kernel<<<nodeTiles, 256, 0, stream>>>(x, pos, Wa, ba, Wp, bp, nodeEmb, N);

    int nTiles = (E + TILE_M - 1) / TILE_M;
    // 3 blocks/CU x 256 CUs, 512 threads each
    edge_mlp_kernel<<<768, 512, 0, stream>>>(nodeEmb, w2p, pos, eidx,
                                             W1, b1, W2, b2, W3, b3,
                                             out, E, nTiles);
}

// Round 13
// 332.027 us; speedup vs baseline: 1.1835x; 1.1835x over previous
//
#include <hip/hip_runtime.h>
#include <hip/hip_bf16.h>
#include <hip/hip_fp16.h>

typedef _Float16 half8 __attribute__((ext_vector_type(8)));
typedef _Float16 half4 __attribute__((ext_vector_type(4)));
typedef __fp16 fp16x2 __attribute__((ext_vector_type(2)));
typedef float floatx4 __attribute__((ext_vector_type(4)));

#define HID 128
#define TILE_M 64

__device__ __forceinline__ float fast_silu(float v) {
    float e = __expf(-v);
    return v * __builtin_amdgcn_rcpf(1.f + e);
}

__device__ __forceinline__ unsigned int pk2(float a, float b) {
    fp16x2 h = __builtin_amdgcn_cvt_pkrtz(a, b);
    return __builtin_bit_cast(unsigned int, h);
}

// LDS-only barrier: drains LDS ops but leaves global (vmcnt) traffic in
// flight. Use ONLY where the barrier guards LDS-LDS hazards exclusively.
__device__ __forceinline__ void barrier_lds_only() {
    asm volatile("s_waitcnt lgkmcnt(0)\n\ts_barrier" ::: "memory");
}

// ---------------------------------------------------------------------------
// Kernel 1: node_emb = [x|pos|0-pad] @ [Wa;Wp;0] + (ba+bp). Block handles a
// 64-node tile via MFMA; output assembled in padded LDS, stored coalesced.
// ---------------------------------------------------------------------------
#define LDO 136
__global__ __launch_bounds__(256) void node_emb_kernel(
    const float* __restrict__ x, const float* __restrict__ pos,
    const float* __restrict__ Wa, const float* __restrict__ ba,
    const float* __restrict__ Wp, const float* __restrict__ bp,
    _Float16* __restrict__ nodeEmb, int N)
{
    __shared__ __align__(16) _Float16 sOut[64 * LDO];   // 17 KB
    const int t    = threadIdx.x;
    const int wave = t >> 6;
    const int lane = t & 63;
    const int quad = lane >> 4;
    const int l16  = lane & 15;

    half8 wf[2];
    floatx4 bias[2];
    #pragma unroll
    for (int ct = 0; ct < 2; ++ct) {
        int col = wave * 32 + ct * 16 + l16;
        #pragma unroll
        for (int j = 0; j < 8; ++j) {
            int k = quad * 8 + j;
            float w = 0.f;
            if (k < 16) w = Wa[k * HID + col];
            else if (k < 19) w = Wp[(k - 16) * HID + col];
            wf[ct][j] = (_Float16)w;
        }
        #pragma unroll
        for (int i = 0; i < 4; ++i) {
            int c2 = wave * 32 + ct * 16 + quad * 4 + i;
            bias[ct][i] = ba[c2] + bp[c2];
        }
    }

    int nTiles = (N + 63) >> 6;
    for (int tile = blockIdx.x; tile < nTiles; tile += gridDim.x) {
        int base = tile * 64;
        half8 af[4];
        #pragma unroll
        for (int rt = 0; rt < 4; ++rt) {
            int node = base + rt * 16 + l16;
            int nd = node < N ? node : N - 1;
            half8 a = (half8){0, 0, 0, 0, 0, 0, 0, 0};
            if (quad < 2) {
                const float* xp = x + (size_t)nd * 16 + quad * 8;
                float4 v0 = *(const float4*)xp;
                float4 v1 = *(const float4*)(xp + 4);
                a[0] = (_Float16)v0.x; a[1] = (_Float16)v0.y;
                a[2] = (_Float16)v0.z; a[3] = (_Float16)v0.w;
                a[4] = (_Float16)v1.x; a[5] = (_Float16)v1.y;
                a[6] = (_Float16)v1.z; a[7] = (_Float16)v1.w;
            } else if (quad == 2) {
                const float* pp = pos + (size_t)nd * 3;
                a[0] = (_Float16)pp[0]; a[1] = (_Float16)pp[1]; a[2] = (_Float16)pp[2];
            }
            af[rt] = a;
        }
        #pragma unroll
        for (int ct = 0; ct < 2; ++ct)
            #pragma unroll
            for (int rt = 0; rt < 4; ++rt) {
                floatx4 d = bias[ct];
                d = __builtin_amdgcn_mfma_f32_16x16x32_f16(wf[ct], af[rt], d, 0, 0, 0);
                half4 hv;
                hv[0] = (_Float16)d[0]; hv[1] = (_Float16)d[1];
                hv[2] = (_Float16)d[2]; hv[3] = (_Float16)d[3];
                *(half4*)&sOut[(rt * 16 + l16) * LDO + wave * 32 + ct * 16 + quad * 4] = hv;
            }
        __syncthreads();
        #pragma unroll
        for (int p = 0; p < 4; ++p) {
            int idx = p * 256 + t;
            int r = idx >> 4, c = idx & 15;
            int node = base + r;
            if (node < N)
                *(half8*)(nodeEmb + (size_t)node * HID + c * 8) =
                    *(const half8*)&sOut[r * LDO + c * 8];
        }
        __syncthreads();
    }
}

// ---------------------------------------------------------------------------
// Kernel 2: per-edge MLP. 512 threads = 8 waves x 16 output cols.
// SESSION-BEST configuration (round 6: edge 260 us, total 330 us, passed).
// Halving the per-wave column slice (vs the 4-wave/32-col round-0 shape)
// halves register-hungry state: w1f 32, w2f 16, acc 16, acc2 16, w3f in
// sW3 LDS table -> VGPR 64, no spill, 4 waves/SIMD at 2 blocks/CU.
// Kept verbatim as final: rounds 7-12 explored every further lever —
//   r7  sH aliasing (LDS 50.7K):  2 blocks still (80KB-partition quantum) -13%
//   r8  TILE_M=32 + (512,8):      forced 64-reg cap -> 2GB spill          -252%
//   r9/r10 TILE_M=32 natural:     global_load_lds race (cover too short)  FAIL
//   r11 reg-staged gather:        race-free but occ 43% (hidden-acc tax)  -7%
//   r12 reg diet to 56:           still 2 blocks (needed <=53)            -27%
// — all bounded by quantized LDS-partition / unified-register limits.
// At this operating point: MfmaUtil 28, VALU 50, HBM 23, occ 41 — no pipe
// saturated; residual is barrier-phase serialization only more resident
// waves could hide, and every path to more waves is closed.
// ---------------------------------------------------------------------------
__global__ __launch_bounds__(512, 4) void edge_mlp_kernel(
    const _Float16* __restrict__ nodeEmb,
    const float* __restrict__ pos,
    const int* __restrict__ eidx,          // [2][E]
    const float* __restrict__ W1, const float* __restrict__ b1,   // [257][128]
    const float* __restrict__ W2, const float* __restrict__ b2,   // [128][128]
    const float* __restrict__ W3, const float* __restrict__ b3,   // [128][4]
    float* __restrict__ out, int E, int nTiles)
{
    __shared__ __align__(16) _Float16 sA[2 * TILE_M * HID];   // 32 KB, XOR swizzle
    __shared__ __align__(16) _Float16 sH1[TILE_M * HID];      // 16 KB, XOR swizzle
    __shared__ __align__(16) _Float16 sH2[TILE_M * HID];      // 16 KB, XOR swizzle
    __shared__ float sDist[TILE_M];
    __shared__ __align__(16) _Float16 sW3[512];               // 1 KB  W3 frags

    const int t    = threadIdx.x;
    const int wave = t >> 6;               // 0..7
    const int lane = t & 63;
    const int quad = lane >> 4;
    const int l16  = lane & 15;
    const int colbase = wave * 16;         // each wave owns 16 output columns

    // ---- stage W3 fragment table into LDS (consumed after first B1) ----
    if (t < 64) {
        int kc = t >> 4, q = (t >> 2) & 3, c = t & 3;
        #pragma unroll
        for (int j = 0; j < 8; ++j)
            sW3[(kc * 16 + q * 4 + c) * 8 + j] =
                (_Float16)W3[(kc * 32 + q * 8 + j) * 4 + c];
    }

    // ---- weight fragments (frag[j] = W[k0+quad*8+j][col]), 1 col-tile/wave ----
    half8 w1f[8];                          // 32 VGPR
    half8 w2f[4];                          // 16 VGPR
    float w1c[4], b1f[4], b2f[4];
    {
        int col = colbase + l16;
        #pragma unroll
        for (int kc = 0; kc < 8; ++kc)
            #pragma unroll
            for (int j = 0; j < 8; ++j)
                w1f[kc][j] = (_Float16)W1[(kc * 32 + quad * 8 + j) * HID + col];
        #pragma unroll
        for (int kc = 0; kc < 4; ++kc)
            #pragma unroll
            for (int j = 0; j < 8; ++j)
                w2f[kc][j] = (_Float16)W2[(kc * 32 + quad * 8 + j) * HID + col];
        #pragma unroll
        for (int i = 0; i < 4; ++i) {
            int c2 = colbase + quad * 4 + i;
            w1c[i] = W1[256 * HID + c2];
            b1f[i] = b1[c2];
            b2f[i] = b2[c2];
        }
    }
    const float b3v0 = b3[0], b3v1 = b3[1], b3v2 = b3[2], b3v3 = b3[3];

    int nid[4];
    float dpre = 0.f;

    auto load_nid = [&](int tl) {
        int eb = tl * TILE_M;
        #pragma unroll
        for (int i = 0; i < 4; ++i) {
            int cid = i * 512 + t;           // 0..2047 chunks of 16B
            int row = cid >> 4;              // 0..127: 0-63 src, 64-127 dst
            int r   = row & 63;
            int e   = eb + r; if (e >= E) e = E - 1;
            nid[i] = (row >> 6) ? eidx[(size_t)E + e] : eidx[e];
        }
    };
    auto load_dist = [&](int tl) -> float {
        if (t >= TILE_M) return 0.f;
        int e = tl * TILE_M + t; if (e >= E) e = E - 1;
        int s = eidx[e], d = eidx[(size_t)E + e];
        float dx = pos[3 * (size_t)s]     - pos[3 * (size_t)d];
        float dy = pos[3 * (size_t)s + 1] - pos[3 * (size_t)d + 1];
        float dz = pos[3 * (size_t)s + 2] - pos[3 * (size_t)d + 2];
        return sqrtf(dx * dx + dy * dy + dz * dz);
    };
    auto dma_issue = [&]() {
        #pragma unroll
        for (int i = 0; i < 4; ++i) {
            int cid = i * 512 + t;
            int row = cid >> 4;
            int cg  = (cid & 15) ^ (row & 15);      // XOR swizzle
            const _Float16* gp = nodeEmb + (size_t)nid[i] * HID + cg * 8;
            __builtin_amdgcn_global_load_lds(
                (__attribute__((address_space(1))) void*)gp,
                (__attribute__((address_space(3))) void*)&sA[(i * 512 + (t & 448)) * 8],
                16, 0, 0);
        }
    };

    bool havePrev = false;
    int prevEbase = 0;
    int tile = blockIdx.x;
    if (tile < nTiles) {
        load_nid(tile);
        dpre = load_dist(tile);
        dma_issue();                         // drains at first B1
    }

    for (; tile < nTiles; tile += gridDim.x) {
        const int ebase = tile * TILE_M;
        if (t < TILE_M) sDist[t] = dpre;
        __syncthreads();                     // B1: DMA(T) drained, sH2(T-1) ready

        // ---- layer 3 of previous tile: waves 0-3 cover the 64 edges ----
        if (havePrev && wave < 4) {
            floatx4 acc3 = (floatx4){0.f, 0.f, 0.f, 0.f};
            #pragma unroll
            for (int kc = 0; kc < 4; ++kc) {
                int slot = ((kc * 4 + quad) ^ l16) * 8;
                half8 h  = *(const half8*)&sH2[(wave * 16 + l16) * HID + slot];
                half8 w3 = *(const half8*)&sW3[(kc * 16 + quad * 4 + (l16 & 3)) * 8];
                acc3 = __builtin_amdgcn_mfma_f32_16x16x32_f16(w3, h, acc3, 0, 0, 0);
            }
            if (quad == 0) {
                int e = prevEbase + wave * 16 + l16;
                if (e < E) {
                    float4 o = {acc3[0] + b3v0, acc3[1] + b3v1,
                                acc3[2] + b3v2, acc3[3] + b3v3};
                    *(float4*)&out[(size_t)e * 4] = o;
                }
            }
        }

        // ---- prefetch next tile metadata (DMA issued post-B2) ----
        int nxt = tile + gridDim.x;
        if (nxt < nTiles) {
            load_nid(nxt);
            dpre = load_dist(nxt);
        }

        // ---- layer 1: bias in acc init, XOR-swizzled sA reads ----
        floatx4 acc[4];
        #pragma unroll
        for (int rt = 0; rt < 4; ++rt) {
            acc[rt][0] = b1f[0]; acc[rt][1] = b1f[1];
            acc[rt][2] = b1f[2]; acc[rt][3] = b1f[3];
        }
        #pragma unroll
        for (int kc = 0; kc < 8; ++kc) {
            int hf   = kc >> 2;
            int cg   = (kc & 3) * 4 + quad;
            int slot = (cg ^ l16) * 8;
            const _Float16* base = &sA[(hf * TILE_M + l16) * HID + slot];
            half8 a0 = *(const half8*)(base + 0 * 16 * HID);
            half8 a1 = *(const half8*)(base + 1 * 16 * HID);
            half8 a2 = *(const half8*)(base + 2 * 16 * HID);
            half8 a3 = *(const half8*)(base + 3 * 16 * HID);
            acc[0] = __builtin_amdgcn_mfma_f32_16x16x32_f16(w1f[kc], a0, acc[0], 0, 0, 0);
            acc[1] = __builtin_amdgcn_mfma_f32_16x16x32_f16(w1f[kc], a1, acc[1], 0, 0, 0);
            acc[2] = __builtin_amdgcn_mfma_f32_16x16x32_f16(w1f[kc], a2, acc[2], 0, 0, 0);
            acc[3] = __builtin_amdgcn_mfma_f32_16x16x32_f16(w1f[kc], a3, acc[3], 0, 0, 0);
        }
        // epilogue 1 -> sH1 (XOR-swizzled uint2 writes)
        #pragma unroll
        for (int rt = 0; rt < 4; ++rt) {
            int m = rt * 16 + l16;
            float d = sDist[m];
            float v0 = fast_silu(fmaf(d, w1c[0], acc[rt][0]));
            float v1 = fast_silu(fmaf(d, w1c[1], acc[rt][1]));
            float v2 = fast_silu(fmaf(d, w1c[2], acc[rt][2]));
            float v3 = fast_silu(fmaf(d, w1c[3], acc[rt][3]));
            uint2 w;
            w.x = pk2(v0, v1);
            w.y = pk2(v2, v3);
            int cgb  = wave * 2 + (quad >> 1);
            int slot = cgb ^ l16;
            *(uint2*)&sH1[m * HID + slot * 8 + (quad & 1) * 4] = w;
        }
        barrier_lds_only();                  // B2: LDS-only; prefetch loads live

        // ---- async DMA for next tile (sA free; overlaps L2+L3+next B1) ----
        if (nxt < nTiles) dma_issue();

        // ---- layer 2 ----
        floatx4 acc2[4];
        #pragma unroll
        for (int rt = 0; rt < 4; ++rt) {
            acc2[rt][0] = b2f[0]; acc2[rt][1] = b2f[1];
            acc2[rt][2] = b2f[2]; acc2[rt][3] = b2f[3];
        }
        #pragma unroll
        for (int kc = 0; kc < 4; ++kc) {
            int slot = ((kc * 4 + quad) ^ l16) * 8;
            half8 a0 = *(const half8*)&sH1[(0 * 16 + l16) * HID + slot];
            half8 a1 = *(const half8*)&sH1[(1 * 16 + l16) * HID + slot];
            half8 a2 = *(const half8*)&sH1[(2 * 16 + l16) * HID + slot];
            half8 a3 = *(const half8*)&sH1[(3 * 16 + l16) * HID + slot];
            acc2[0] = __builtin_amdgcn_mfma_f32_16x16x32_f16(w2f[kc], a0, acc2[0], 0, 0, 0);
            acc2[1] = __builtin_amdgcn_mfma_f32_16x16x32_f16(w2f[kc], a1, acc2[1], 0, 0, 0);
            acc2[2] = __builtin_amdgcn_mfma_f32_16x16x32_f16(w2f[kc], a2, acc2[2], 0, 0, 0);
            acc2[3] = __builtin_amdgcn_mfma_f32_16x16x32_f16(w2f[kc], a3, acc2[3], 0, 0, 0);
        }
        // epilogue 2 -> sH2 (all waves' L3(T-1) reads finished before B2)
        #pragma unroll
        for (int rt = 0; rt < 4; ++rt) {
            int m = rt * 16 + l16;
            float v0 = fast_silu(acc2[rt][0]);
            float v1 = fast_silu(acc2[rt][1]);
            float v2 = fast_silu(acc2[rt][2]);
            float v3 = fast_silu(acc2[rt][3]);
            uint2 w;
            w.x = pk2(v0, v1);
            w.y = pk2(v2, v3);
            int cgb  = wave * 2 + (quad >> 1);
            int slot = cgb ^ l16;
            *(uint2*)&sH2[m * HID + slot * 8 + (quad & 1) * 4] = w;
        }
        havePrev = true;
        prevEbase = ebase;
    }

    // ---- flush: layer 3 of the final tile ----
    if (havePrev) {
        __syncthreads();
        if (wave < 4) {
            floatx4 acc3 = (floatx4){0.f, 0.f, 0.f, 0.f};
            #pragma unroll
            for (int kc = 0; kc < 4; ++kc) {
                int slot = ((kc * 4 + quad) ^ l16) * 8;
                half8 h  = *(const half8*)&sH2[(wave * 16 + l16) * HID + slot];
                half8 w3 = *(const half8*)&sW3[(kc * 16 + quad * 4 + (l16 & 3)) * 8];
                acc3 = __builtin_amdgcn_mfma_f32_16x16x32_f16(w3, h, acc3, 0, 0, 0);
            }
            if (quad == 0) {
                int e = prevEbase + wave * 16 + l16;
                if (e < E) {
                    float4 o = {acc3[0] + b3v0, acc3[1] + b3v1,
                                acc3[2] + b3v2, acc3[3] + b3v3};
                    *(float4*)&out[(size_t)e * 4] = o;
                }
            }
        }
    }
}

extern "C" void kernel_launch(void* const* d_in, const int* in_sizes, int n_in,
                              void* d_out, int out_size, void* d_ws, size_t ws_size,
                              hipStream_t stream) {
    const float* x   = (const float*)d_in[0];
    const float* pos = (const float*)d_in[1];
    const int*  eidx = (const int*)d_in[2];
    const float* Wa = (const float*)d_in[3];
    const float* ba = (const float*)d_in[4];
    const float* Wp = (const float*)d_in[5];
    const float* bp = (const float*)d_in[6];
    const float* W1 = (const float*)d_in[7];
    const float* b1 = (const float*)d_in[8];
    const float* W2 = (const float*)d_in[9];
    const float* b2 = (const float*)d_in[10];
    const float* W3 = (const float*)d_in[11];
    const float* b3 = (const float*)d_in[12];
    float* out = (float*)d_out;

    int N = in_sizes[0] / 16;   // ATOM_DIM
    int E = in_sizes[2] / 2;

    _Float16* nodeEmb = (_Float16*)d_ws;   // N*128 fp16 = 25.6 MB

    int nodeTiles = (N + 63) / 64;
    node_emb_kernel<<<nodeTiles, 256, 0, stream>>>(x, pos, Wa, ba, Wp, bp, nodeEmb, N);

    int nTiles = (E + TILE_M - 1) / TILE_M;
    // 2 blocks/CU x 256 CUs, 512 threads each
    edge_mlp_kernel<<<512, 512, 0, stream>>>(nodeEmb, pos, eidx,
                                             W1, b1, W2, b2, W3, b3,
                                             out, E, nTiles);
}